// Round 13
// baseline (918.346 us; speedup 1.0000x reference)
//
#include <hip/hip_runtime.h>

#define N_NODES 50000
#define E1N 1600000
#define M_PAIRS 200000
#define E2N 3200000
#define P_OUT 20000
#define EPSF 1e-5f

#define RED_BLOCKS 512
#define RANGE 16384            // histogram counters per block (64 KB LDS)
#define NR1 4                  // ceil(N_NODES/RANGE)
#define NR2 13                 // ceil(M_PAIRS/RANGE)
#define BPG 16                 // blocks per range-group

// ---------------- stats offsets within stats buffer (floats) ----------------
#define S0_SUM   0
#define S0_SQ    32
#define S_A0     64
#define S_B0ROW  96
#define S1_SUM   128
#define S1_SQ    160
#define S_A1     192
#define S_B1     224
#define S_CNT    256   // int
#define S_ZC0    288
#define S_ZC1    320
#define S3_SUM   352
#define S3_SQ    384
#define S_A3     416
#define S_B3     448
#define S_TOTAL  512

__device__ __forceinline__ void f4add(float4& a, const float4 b) {
    a.x += b.x; a.y += b.y; a.z += b.z; a.w += b.w;
}

// block-level reduce of per-thread float4 partials (feature group = (tid&7)*4)
__device__ __forceinline__ void stats_block_reduce(float4 s, float4 q,
                                                   float* __restrict__ sum,
                                                   float* __restrict__ sumsq) {
    __shared__ float4 ss[256], sq[256];
    int tid = threadIdx.x;
    ss[tid] = s; sq[tid] = q;
    __syncthreads();
    #pragma unroll
    for (int st = 128; st >= 8; st >>= 1) {
        if (tid < st) { f4add(ss[tid], ss[tid + st]); f4add(sq[tid], sq[tid + st]); }
        __syncthreads();
    }
    if (tid < 8) {
        int base = tid * 4;
        float4 fs = ss[tid], fq = sq[tid];
        atomicAdd(&sum[base + 0], fs.x);
        atomicAdd(&sum[base + 1], fs.y);
        atomicAdd(&sum[base + 2], fs.z);
        atomicAdd(&sum[base + 3], fs.w);
        atomicAdd(&sumsq[base + 0], fq.x);
        atomicAdd(&sumsq[base + 1], fq.y);
        atomicAdd(&sumsq[base + 2], fq.z);
        atomicAdd(&sumsq[base + 3], fq.w);
    }
}

// gather embedding rows (float4 granularity), store e, accumulate gn0 stats
__global__ void k_embed_stats(const float* __restrict__ emb, const int* __restrict__ x,
                              float* __restrict__ e, float* __restrict__ sum,
                              float* __restrict__ sumsq, int n) {
    long n4 = (long)n * 8;
    float4 s = {0,0,0,0}, q = {0,0,0,0};
    float4* e4 = (float4*)e;
    long stride = (long)gridDim.x * 256;
    for (long i = (long)blockIdx.x * 256 + threadIdx.x; i < n4; i += stride) {
        int node = (int)(i >> 3), fg = ((int)i & 7) * 4;
        int xr = x[node];
        float4 v = *(const float4*)&emb[(long)xr * 32 + fg];
        e4[i] = v;
        s.x += v.x; s.y += v.y; s.z += v.z; s.w += v.w;
        q.x += v.x * v.x; q.y += v.y * v.y; q.z += v.z * v.z; q.w += v.w * v.w;
    }
    stats_block_reduce(s, q, sum, sumsq);
}

// GraphNorm -> per-feature affine A,B.  y = A*x + B
__global__ void k_affine32(const float* __restrict__ sum, const float* __restrict__ sumsq,
                           const float* __restrict__ w, const float* __restrict__ b,
                           const float* __restrict__ ms, float invN,
                           float* __restrict__ A, float* __restrict__ B) {
    int f = threadIdx.x;  // 32 threads
    float mean = sum[f] * invN;
    float c = ms[f] * mean;
    float var = sumsq[f] * invN - 2.f * c * mean + c * c;
    float rs = rsqrtf(var + EPSF);
    A[f] = w[f] * rs;
    B[f] = b[f] - w[f] * rs * c;
}

// gn0 affine + fold shift through c1_W:  A[f], brow[o] = sum_f B[f]*W[f][o]
__global__ void k_affine_fold(const float* __restrict__ sum, const float* __restrict__ sumsq,
                              const float* __restrict__ w, const float* __restrict__ b,
                              const float* __restrict__ ms, float invN,
                              const float* __restrict__ W,
                              float* __restrict__ A, float* __restrict__ brow) {
    __shared__ float Bl[32];
    int f = threadIdx.x;  // 32 threads
    float mean = sum[f] * invN;
    float c = ms[f] * mean;
    float var = sumsq[f] * invN - 2.f * c * mean + c * c;
    float rs = rsqrtf(var + EPSF);
    A[f] = w[f] * rs;
    Bl[f] = b[f] - w[f] * rs * c;
    __syncthreads();
    float s = 0.f;
    #pragma unroll
    for (int f2 = 0; f2 < 32; f2++) s += Bl[f2] * W[f2 * 32 + f];
    brow[f] = s;
}

// u[i][o] = (sum_f (A[f]*e[i][f]) * W[f][o] + brow[o]) * dscale[i]
__global__ void k_mm32s(const float* __restrict__ e, const float* __restrict__ W,
                        const float* __restrict__ A, const float* __restrict__ brow,
                        const float* __restrict__ dscale, float* __restrict__ t, int n) {
    __shared__ float Wp[32][32];
    __shared__ float rows[8][32];
    int lt = threadIdx.x;
    for (int k = lt; k < 1024; k += 256) {
        int f = k >> 5;
        Wp[f][k & 31] = A[f] * W[k];
    }
    int nl = lt >> 5, o = lt & 31;
    int node = blockIdx.x * 8 + nl;
    if (node < n) rows[nl][o] = e[(long)node * 32 + o];
    __syncthreads();
    if (node < n) {
        float acc = brow[o];
        #pragma unroll
        for (int f = 0; f < 32; f++) acc += rows[nl][f] * Wp[f][o];
        t[(long)node * 32 + o] = acc * dscale[node];
    }
}

// hw[i][o] = sum_f relu(A[f]*g[i][f]+B[f]) * W[f][o]   (fused gn1 affine+ReLU)
__global__ void k_mm32_relu_in(const float* __restrict__ g, const float* __restrict__ W,
                               const float* __restrict__ A, const float* __restrict__ B,
                               float* __restrict__ hw, int n) {
    __shared__ float Wp[32][32];
    __shared__ float rows[8][32];
    int lt = threadIdx.x;
    for (int k = lt; k < 1024; k += 256) {
        Wp[k >> 5][k & 31] = W[k];
    }
    int nl = lt >> 5, o = lt & 31;
    int node = blockIdx.x * 8 + nl;
    if (node < n) rows[nl][o] = fmaxf(A[o] * g[(long)node * 32 + o] + B[o], 0.f);
    __syncthreads();
    if (node < n) {
        float acc = 0.f;
        #pragma unroll
        for (int f = 0; f < 32; f++) acc += rows[nl][f] * Wp[f][o];
        hw[(long)node * 32 + o] = acc;
    }
}

// ---------------- degree via LDS partial histograms (no global atomics) ----------------
__global__ __launch_bounds__(256) void k_deg_hist(const int* __restrict__ e1col,
                                                  const int* __restrict__ e2col,
                                                  int* __restrict__ pbuf) {
    __shared__ int h[RANGE];   // 64 KB
    int tid = threadIdx.x;
    for (int i = tid; i < RANGE; i += 256) h[i] = 0;
    __syncthreads();
    int gid = blockIdx.x / BPG;
    int blk = blockIdx.x % BPG;
    const int* col; long ne; int base;
    if (gid < NR1) { col = e1col; ne = E1N; base = gid * RANGE; }
    else           { col = e2col; ne = E2N; base = (gid - NR1) * RANGE; }
    for (long i = (long)blk * 256 + tid; i < ne; i += (long)BPG * 256) {
        unsigned c = (unsigned)(col[i] - base);
        if (c < RANGE) atomicAdd(&h[c], 1);
    }
    __syncthreads();
    int* dst = pbuf + ((size_t)gid * BPG + blk) * RANGE;
    for (int i = tid; i < RANGE; i += 256) dst[i] = h[i];
}

// reduce BPG partials per node -> dinv = rsqrt(deg+1); handles both graphs
__global__ void k_deg_reduce(const int* __restrict__ pbuf,
                             float* __restrict__ d1, float* __restrict__ d2) {
    int idx = blockIdx.x * 256 + threadIdx.x;
    if (idx < N_NODES) {
        int g = idx / RANGE, off = idx % RANGE;
        const int* p = pbuf + ((size_t)g * BPG) * RANGE + off;
        int s = 0;
        #pragma unroll
        for (int b = 0; b < BPG; b++) s += p[(size_t)b * RANGE];
        d1[idx] = rsqrtf((float)s + 1.f);
    } else if (idx - N_NODES < M_PAIRS) {
        int j = idx - N_NODES;
        int g = j / RANGE, off = j % RANGE;
        const int* p = pbuf + ((size_t)(NR1 + g) * BPG) * RANGE + off;
        int s = 0;
        #pragma unroll
        for (int b = 0; b < BPG; b++) s += p[(size_t)b * RANGE];
        d2[j] = rsqrtf((float)s + 1.f);
    }
}

// coalesced atomic scatter: agg[col][f] += u[row][f]   (conv1 instance)
__global__ void k_scatter1(const int* __restrict__ row, const int* __restrict__ col,
                           const float* __restrict__ u, float* __restrict__ agg, int ne) {
    long idx = (long)blockIdx.x * 256 + threadIdx.x;
    if (idx >= (long)ne * 32) return;
    int e = (int)(idx >> 5), f = (int)idx & 31;
    atomicAdd(&agg[(long)col[e] * 32 + f], u[(long)row[e] * 32 + f]);
}

// identical body, distinct symbol for profiling (conv2 instance)
__global__ void k_scatter2(const int* __restrict__ row, const int* __restrict__ col,
                           const float* __restrict__ u, float* __restrict__ agg, int ne) {
    long idx = (long)blockIdx.x * 256 + threadIdx.x;
    if (idx >= (long)ne * 32) return;
    int e = (int)(idx >> 5), f = (int)idx & 31;
    atomicAdd(&agg[(long)col[e] * 32 + f], u[(long)row[e] * 32 + f]);
}

// epilogue: agg = dinv[i]*(agg + u) + bias, fused GraphNorm stats accumulation
__global__ void k_selfbias_stats(float* __restrict__ agg, const float* __restrict__ u,
                                 const float* __restrict__ dinv, const float* __restrict__ bias,
                                 float* __restrict__ sum, float* __restrict__ sumsq, int n) {
    long n4 = (long)n * 8;
    float4 s = {0,0,0,0}, q = {0,0,0,0};
    float4* a4 = (float4*)agg;
    const float4* u4 = (const float4*)u;
    long stride = (long)gridDim.x * 256;
    for (long idx = (long)blockIdx.x * 256 + threadIdx.x; idx < n4; idx += stride) {
        int i = (int)(idx >> 3), fg = ((int)idx & 7) * 4;
        float dc = dinv[i];
        float4 a = a4[idx];
        float4 uv = u4[idx];
        float4 b = *(const float4*)&bias[fg];
        float4 r;
        r.x = dc * (a.x + uv.x) + b.x;
        r.y = dc * (a.y + uv.y) + b.y;
        r.z = dc * (a.z + uv.z) + b.z;
        r.w = dc * (a.w + uv.w) + b.w;
        a4[idx] = r;
        s.x += r.x; s.y += r.y; s.z += r.z; s.w += r.w;
        q.x += r.x * r.x; q.y += r.y * r.y; q.z += r.z * r.z; q.w += r.w * r.w;
    }
    stats_block_reduce(s, q, sum, sumsq);
}

// fused: set mask[pos2[i]]=1 (dedup via atomicExch) and count distinct
__global__ void k_mask_count(const int* __restrict__ pos2, int* __restrict__ mask,
                             int* __restrict__ cnt, int p) {
    int i = blockIdx.x * 256 + threadIdx.x;
    int add = 0;
    if (i < p) {
        int old = atomicExch(&mask[pos2[i]], 1);
        add = (old == 0) ? 1 : 0;
    }
    __shared__ int sd[256];
    sd[threadIdx.x] = add;
    __syncthreads();
    for (int s = 128; s > 0; s >>= 1) {
        if (threadIdx.x < s) sd[threadIdx.x] += sd[threadIdx.x + s];
        __syncthreads();
    }
    if (threadIdx.x == 0 && sd[0]) atomicAdd(cnt, sd[0]);
}

// z has only two distinct rows (mask 0/1); zc{0,1}[o] = z{0,1} @ c2_W[32:48]
__global__ void k_zcalc(const float* __restrict__ emb2, const float* __restrict__ w,
                        const float* __restrict__ b, const float* __restrict__ ms,
                        const int* __restrict__ cnt, const float* __restrict__ c2W,
                        float* __restrict__ zc0, float* __restrict__ zc1) {
    __shared__ float z0[16], z1[16];
    int t = threadIdx.x;  // 32 threads
    const float Mf = (float)M_PAIRS;
    if (t < 16) {
        float e0 = emb2[t], e1 = emb2[16 + t];
        float c1f = (float)(*cnt);
        float mean = (c1f * e1 + (Mf - c1f) * e0) / Mf;
        float c = ms[t] * mean;
        float d0 = e0 - c, d1 = e1 - c;
        float var = (c1f * d1 * d1 + (Mf - c1f) * d0 * d0) / Mf;
        float rs = rsqrtf(var + EPSF);
        z0[t] = w[t] * d0 * rs + b[t];
        z1[t] = w[t] * d1 * rs + b[t];
    }
    __syncthreads();
    float s0 = 0.f, s1 = 0.f;
    #pragma unroll
    for (int f = 0; f < 16; f++) {
        float wv = c2W[(32 + f) * 32 + t];
        s0 += z0[f] * wv;
        s1 += z1[f] * wv;
    }
    zc0[t] = s0;
    zc1[t] = s1;
}

// t2[j][fg..] = (hw[a][fg..] + hw[b][fg..] + zc_{mask[j]}[fg..]) * d2[j]
__global__ void k_t2(const float* __restrict__ hw, const int* __restrict__ pos1,
                     const int* __restrict__ mask, const float* __restrict__ zc0,
                     const float* __restrict__ zc1, const float* __restrict__ d2,
                     float* __restrict__ t2, int m) {
    long idx = (long)blockIdx.x * 256 + threadIdx.x;
    if (idx >= (long)m * 8) return;
    int j = (int)(idx >> 3), fg = ((int)idx & 7) * 4;
    int a = pos1[2 * j], b = pos1[2 * j + 1];
    const float* zc = mask[j] ? zc1 : zc0;
    float dj = d2[j];
    float4 va = *(const float4*)&hw[(long)a * 32 + fg];
    float4 vb = *(const float4*)&hw[(long)b * 32 + fg];
    float4 vz = *(const float4*)&zc[fg];
    float4 r;
    r.x = (va.x + vb.x + vz.x) * dj;
    r.y = (va.y + vb.y + vz.y) * dj;
    r.z = (va.z + vb.z + vz.z) * dj;
    r.w = (va.w + vb.w + vz.w) * dj;
    *(float4*)&t2[idx * 4] = r;
}

// out[k] = relu(A*g2[pos2[k]]+B) . predW + predb
__global__ void k_pred(const float* __restrict__ g2, const int* __restrict__ pos2,
                       const float* __restrict__ A, const float* __restrict__ B,
                       const float* __restrict__ predW, const float* __restrict__ predb,
                       float* __restrict__ out, int p) {
    int k = blockIdx.x * 256 + threadIdx.x;
    if (k >= p) return;
    int j = pos2[k];
    float s = predb[0];
    #pragma unroll
    for (int o = 0; o < 32; o++)
        s += fmaxf(A[o] * g2[(long)j * 32 + o] + B[o], 0.f) * predW[o];
    out[k] = s;
}

extern "C" void kernel_launch(void* const* d_in, const int* in_sizes, int n_in,
                              void* d_out, int out_size, void* d_ws, size_t ws_size,
                              hipStream_t stream) {
    const int*   x      = (const int*)d_in[0];
    const int*   e1row  = (const int*)d_in[1];
    const int*   e1col  = e1row + E1N;
    const int*   e2row  = (const int*)d_in[2];
    const int*   e2col  = e2row + E2N;
    const int*   pos1   = (const int*)d_in[3];
    const int*   pos2   = (const int*)d_in[4];
    const float* emb1   = (const float*)d_in[5];
    const float* gn0_w  = (const float*)d_in[6];
    const float* gn0_b  = (const float*)d_in[7];
    const float* gn0_ms = (const float*)d_in[8];
    const float* c1_W   = (const float*)d_in[9];
    const float* c1_b   = (const float*)d_in[10];
    const float* gn1_w  = (const float*)d_in[11];
    const float* gn1_b  = (const float*)d_in[12];
    const float* gn1_ms = (const float*)d_in[13];
    const float* emb2   = (const float*)d_in[14];
    const float* gn2_w  = (const float*)d_in[15];
    const float* gn2_b  = (const float*)d_in[16];
    const float* gn2_ms = (const float*)d_in[17];
    const float* c2_W   = (const float*)d_in[18];
    const float* c2_b   = (const float*)d_in[19];
    const float* gn3_w  = (const float*)d_in[20];
    const float* gn3_b  = (const float*)d_in[21];
    const float* gn3_ms = (const float*)d_in[22];
    const float* predW  = (const float*)d_in[23];
    const float* predb  = (const float*)d_in[24];
    float* out = (float*)d_out;

    // ---------------- workspace arena (floats) ----------------
    const size_t N32 = (size_t)N_NODES * 32;
    const size_t M32 = (size_t)M_PAIRS * 32;
    float* fw = (float*)d_ws;
    size_t off = 0;
    auto alloc = [&](size_t n) { float* p = fw + off; off += n; return p; };
    float* e    = alloc(N32);               // alias hw later
    float* t    = alloc(N32);               // u1 = (gn0(e)@W + brow) * d1
    float* t2   = alloc(M32);               // u2
    int*   pbuf = (int*)alloc((size_t)(NR1 + NR2) * BPG * RANGE);  // ~17.8 MB
    float* d1   = alloc(N_NODES);
    float* d2   = alloc(M_PAIRS);
    // ---- contiguous zero region ----
    float* agg  = alloc(N32);
    float* agg2 = alloc(M32);
    int*   mask = (int*)alloc(M_PAIRS);
    float* st   = alloc(S_TOTAL);
    float* hw   = e;  // alias: e dead after k_mm32s

    const size_t zero_bytes = (N32 + M32 + (size_t)M_PAIRS + S_TOTAL) * 4;
    hipMemsetAsync(agg, 0, zero_bytes, stream);

    auto cdiv = [](long a, long b) { return (int)((a + b - 1) / b); };
    const float invN = 1.f / (float)N_NODES;
    const float invM = 1.f / (float)M_PAIRS;

    // ---- degrees via LDS partial histograms (no global atomics) ----
    k_deg_hist<<<(NR1 + NR2) * BPG, 256, 0, stream>>>(e1col, e2col, pbuf);
    k_deg_reduce<<<cdiv((long)N_NODES + M_PAIRS, 256), 256, 0, stream>>>(pbuf, d1, d2);

    // ---- stage 0: embedding + gn0 stats ----
    k_embed_stats<<<RED_BLOCKS, 256, 0, stream>>>(emb1, x, e, st + S0_SUM, st + S0_SQ, N_NODES);
    k_affine_fold<<<1, 32, 0, stream>>>(st + S0_SUM, st + S0_SQ, gn0_w, gn0_b, gn0_ms, invN,
                                        c1_W, st + S_A0, st + S_B0ROW);

    // ---- conv1: u1 = (gn0(e) @ c1_W) * d1 ; scatter ; epilogue+gn1 stats ----
    k_mm32s<<<cdiv(N_NODES, 8), 256, 0, stream>>>(e, c1_W, st + S_A0, st + S_B0ROW, d1, t, N_NODES);
    k_scatter1<<<cdiv((long)E1N * 32, 256), 256, 0, stream>>>(e1row, e1col, t, agg, E1N);
    k_selfbias_stats<<<RED_BLOCKS, 256, 0, stream>>>(agg, t, d1, c1_b,
                                                     st + S1_SUM, st + S1_SQ, N_NODES);
    k_affine32<<<1, 32, 0, stream>>>(st + S1_SUM, st + S1_SQ, gn1_w, gn1_b, gn1_ms, invN,
                                     st + S_A1, st + S_B1);
    k_mm32_relu_in<<<cdiv(N_NODES, 8), 256, 0, stream>>>(agg, c2_W, st + S_A1, st + S_B1,
                                                         hw, N_NODES);

    // ---- mask / z path ----
    k_mask_count<<<cdiv(P_OUT, 256), 256, 0, stream>>>(pos2, mask, (int*)(st + S_CNT), P_OUT);
    k_zcalc<<<1, 32, 0, stream>>>(emb2, gn2_w, gn2_b, gn2_ms, (const int*)(st + S_CNT),
                                  c2_W, st + S_ZC0, st + S_ZC1);

    // ---- conv2: u2 = (hw[a]+hw[b]+zc) * d2 ; scatter ; epilogue+gn3 stats ----
    k_t2<<<cdiv((long)M_PAIRS * 8, 256), 256, 0, stream>>>(hw, pos1, mask, st + S_ZC0,
                                                           st + S_ZC1, d2, t2, M_PAIRS);
    k_scatter2<<<cdiv((long)E2N * 32, 256), 256, 0, stream>>>(e2row, e2col, t2, agg2, E2N);
    k_selfbias_stats<<<RED_BLOCKS, 256, 0, stream>>>(agg2, t2, d2, c2_b,
                                                     st + S3_SUM, st + S3_SQ, M_PAIRS);
    k_affine32<<<1, 32, 0, stream>>>(st + S3_SUM, st + S3_SQ, gn3_w, gn3_b, gn3_ms, invM,
                                     st + S_A3, st + S_B3);
    k_pred<<<cdiv(P_OUT, 256), 256, 0, stream>>>(agg2, pos2, st + S_A3, st + S_B3,
                                                 predW, predb, out, P_OUT);
}

// Round 14
// 763.054 us; speedup vs baseline: 1.2035x; 1.2035x over previous
//
#include <hip/hip_runtime.h>

#define N_NODES 50000
#define E1N 1600000
#define M_PAIRS 200000
#define E2N 3200000
#define P_OUT 20000
#define EPSF 1e-5f

#define RED_BLOCKS 512
#define RANGE_N 32768          // nodes per histogram group (packed 2/int, 64 KB LDS)
#define HWORDS (RANGE_N / 2)   // 16384 ints
#define NR1 2                  // ceil(N_NODES/RANGE_N)
#define NR2 7                  // ceil(M_PAIRS/RANGE_N)
#define NGR (NR1 + NR2)        // 9 groups
#define BPG 56                 // blocks per group -> 504 blocks ~= 2/CU (LDS limit)

// ---------------- stats offsets within stats buffer (floats) ----------------
#define S0_SUM   0
#define S0_SQ    32
#define S_A0     64
#define S_B0ROW  96
#define S1_SUM   128
#define S1_SQ    160
#define S_A1     192
#define S_B1     224
#define S_CNT    256   // int
#define S_ZC0    288
#define S_ZC1    320
#define S3_SUM   352
#define S3_SQ    384
#define S_A3     416
#define S_B3     448
#define S_TOTAL  512

__device__ __forceinline__ void f4add(float4& a, const float4 b) {
    a.x += b.x; a.y += b.y; a.z += b.z; a.w += b.w;
}

// block-level reduce of per-thread float4 partials (feature group = (tid&7)*4)
__device__ __forceinline__ void stats_block_reduce(float4 s, float4 q,
                                                   float* __restrict__ sum,
                                                   float* __restrict__ sumsq) {
    __shared__ float4 ss[256], sq[256];
    int tid = threadIdx.x;
    ss[tid] = s; sq[tid] = q;
    __syncthreads();
    #pragma unroll
    for (int st = 128; st >= 8; st >>= 1) {
        if (tid < st) { f4add(ss[tid], ss[tid + st]); f4add(sq[tid], sq[tid + st]); }
        __syncthreads();
    }
    if (tid < 8) {
        int base = tid * 4;
        float4 fs = ss[tid], fq = sq[tid];
        atomicAdd(&sum[base + 0], fs.x);
        atomicAdd(&sum[base + 1], fs.y);
        atomicAdd(&sum[base + 2], fs.z);
        atomicAdd(&sum[base + 3], fs.w);
        atomicAdd(&sumsq[base + 0], fq.x);
        atomicAdd(&sumsq[base + 1], fq.y);
        atomicAdd(&sumsq[base + 2], fq.z);
        atomicAdd(&sumsq[base + 3], fq.w);
    }
}

// gather embedding rows (float4 granularity), store e, accumulate gn0 stats
__global__ void k_embed_stats(const float* __restrict__ emb, const int* __restrict__ x,
                              float* __restrict__ e, float* __restrict__ sum,
                              float* __restrict__ sumsq, int n) {
    long n4 = (long)n * 8;
    float4 s = {0,0,0,0}, q = {0,0,0,0};
    float4* e4 = (float4*)e;
    long stride = (long)gridDim.x * 256;
    for (long i = (long)blockIdx.x * 256 + threadIdx.x; i < n4; i += stride) {
        int node = (int)(i >> 3), fg = ((int)i & 7) * 4;
        int xr = x[node];
        float4 v = *(const float4*)&emb[(long)xr * 32 + fg];
        e4[i] = v;
        s.x += v.x; s.y += v.y; s.z += v.z; s.w += v.w;
        q.x += v.x * v.x; q.y += v.y * v.y; q.z += v.z * v.z; q.w += v.w * v.w;
    }
    stats_block_reduce(s, q, sum, sumsq);
}

// GraphNorm -> per-feature affine A,B.  y = A*x + B
__global__ void k_affine32(const float* __restrict__ sum, const float* __restrict__ sumsq,
                           const float* __restrict__ w, const float* __restrict__ b,
                           const float* __restrict__ ms, float invN,
                           float* __restrict__ A, float* __restrict__ B) {
    int f = threadIdx.x;  // 32 threads
    float mean = sum[f] * invN;
    float c = ms[f] * mean;
    float var = sumsq[f] * invN - 2.f * c * mean + c * c;
    float rs = rsqrtf(var + EPSF);
    A[f] = w[f] * rs;
    B[f] = b[f] - w[f] * rs * c;
}

// gn0 affine + fold shift through c1_W:  A[f], brow[o] = sum_f B[f]*W[f][o]
__global__ void k_affine_fold(const float* __restrict__ sum, const float* __restrict__ sumsq,
                              const float* __restrict__ w, const float* __restrict__ b,
                              const float* __restrict__ ms, float invN,
                              const float* __restrict__ W,
                              float* __restrict__ A, float* __restrict__ brow) {
    __shared__ float Bl[32];
    int f = threadIdx.x;  // 32 threads
    float mean = sum[f] * invN;
    float c = ms[f] * mean;
    float var = sumsq[f] * invN - 2.f * c * mean + c * c;
    float rs = rsqrtf(var + EPSF);
    A[f] = w[f] * rs;
    Bl[f] = b[f] - w[f] * rs * c;
    __syncthreads();
    float s = 0.f;
    #pragma unroll
    for (int f2 = 0; f2 < 32; f2++) s += Bl[f2] * W[f2 * 32 + f];
    brow[f] = s;
}

// u[i][o] = (sum_f (A[f]*e[i][f]) * W[f][o] + brow[o]) * dscale[i]
__global__ void k_mm32s(const float* __restrict__ e, const float* __restrict__ W,
                        const float* __restrict__ A, const float* __restrict__ brow,
                        const float* __restrict__ dscale, float* __restrict__ t, int n) {
    __shared__ float Wp[32][32];
    __shared__ float rows[8][32];
    int lt = threadIdx.x;
    for (int k = lt; k < 1024; k += 256) {
        int f = k >> 5;
        Wp[f][k & 31] = A[f] * W[k];
    }
    int nl = lt >> 5, o = lt & 31;
    int node = blockIdx.x * 8 + nl;
    if (node < n) rows[nl][o] = e[(long)node * 32 + o];
    __syncthreads();
    if (node < n) {
        float acc = brow[o];
        #pragma unroll
        for (int f = 0; f < 32; f++) acc += rows[nl][f] * Wp[f][o];
        t[(long)node * 32 + o] = acc * dscale[node];
    }
}

// hw[i][o] = sum_f relu(A[f]*g[i][f]+B[f]) * W[f][o]   (fused gn1 affine+ReLU)
__global__ void k_mm32_relu_in(const float* __restrict__ g, const float* __restrict__ W,
                               const float* __restrict__ A, const float* __restrict__ B,
                               float* __restrict__ hw, int n) {
    __shared__ float Wp[32][32];
    __shared__ float rows[8][32];
    int lt = threadIdx.x;
    for (int k = lt; k < 1024; k += 256) {
        Wp[k >> 5][k & 31] = W[k];
    }
    int nl = lt >> 5, o = lt & 31;
    int node = blockIdx.x * 8 + nl;
    if (node < n) rows[nl][o] = fmaxf(A[o] * g[(long)node * 32 + o] + B[o], 0.f);
    __syncthreads();
    if (node < n) {
        float acc = 0.f;
        #pragma unroll
        for (int f = 0; f < 32; f++) acc += rows[nl][f] * Wp[f][o];
        hw[(long)node * 32 + o] = acc;
    }
}

// ---------------- degree via PACKED 16-bit LDS histograms ----------------
// 32768 nodes per group packed 2/int in 64 KB LDS; per-block per-node counts
// are far below 2^16 so halfword counters cannot overflow.
__global__ __launch_bounds__(256) void k_deg_hist(const int* __restrict__ e1col,
                                                  const int* __restrict__ e2col,
                                                  int* __restrict__ pbuf) {
    __shared__ int h[HWORDS];   // 64 KB
    int tid = threadIdx.x;
    for (int i = tid; i < HWORDS; i += 256) h[i] = 0;
    __syncthreads();
    int gid = blockIdx.x / BPG;
    int blk = blockIdx.x % BPG;
    const int* col; long ne; int base;
    if (gid < NR1) { col = e1col; ne = E1N; base = gid * RANGE_N; }
    else           { col = e2col; ne = E2N; base = (gid - NR1) * RANGE_N; }
    for (long i = (long)blk * 256 + tid; i < ne; i += (long)BPG * 256) {
        unsigned c = (unsigned)(col[i] - base);
        if (c < RANGE_N) atomicAdd(&h[c >> 1], 1 << ((c & 1) * 16));
    }
    __syncthreads();
    int* dst = pbuf + ((size_t)gid * BPG + blk) * HWORDS;
    for (int i = tid; i < HWORDS; i += 256) dst[i] = h[i];
}

// reduce BPG packed partials per node -> dinv = rsqrt(deg+1); both graphs
__global__ void k_deg_reduce(const int* __restrict__ pbuf,
                             float* __restrict__ d1, float* __restrict__ d2) {
    int idx = blockIdx.x * 256 + threadIdx.x;
    if (idx < N_NODES) {
        int g = idx / RANGE_N, off = idx % RANGE_N;
        const int* p = pbuf + ((size_t)g * BPG) * HWORDS + (off >> 1);
        int sh = (off & 1) * 16;
        int s = 0;
        #pragma unroll
        for (int b = 0; b < BPG; b++) s += (p[(size_t)b * HWORDS] >> sh) & 0xFFFF;
        d1[idx] = rsqrtf((float)s + 1.f);
    } else if (idx - N_NODES < M_PAIRS) {
        int j = idx - N_NODES;
        int g = j / RANGE_N, off = j % RANGE_N;
        const int* p = pbuf + ((size_t)(NR1 + g) * BPG) * HWORDS + (off >> 1);
        int sh = (off & 1) * 16;
        int s = 0;
        #pragma unroll
        for (int b = 0; b < BPG; b++) s += (p[(size_t)b * HWORDS] >> sh) & 0xFFFF;
        d2[j] = rsqrtf((float)s + 1.f);
    }
}

// coalesced atomic scatter: agg[col][f] += u[row][f]   (conv1 instance)
__global__ void k_scatter1(const int* __restrict__ row, const int* __restrict__ col,
                           const float* __restrict__ u, float* __restrict__ agg, int ne) {
    long idx = (long)blockIdx.x * 256 + threadIdx.x;
    if (idx >= (long)ne * 32) return;
    int e = (int)(idx >> 5), f = (int)idx & 31;
    atomicAdd(&agg[(long)col[e] * 32 + f], u[(long)row[e] * 32 + f]);
}

// identical body, distinct symbol for profiling (conv2 instance)
__global__ void k_scatter2(const int* __restrict__ row, const int* __restrict__ col,
                           const float* __restrict__ u, float* __restrict__ agg, int ne) {
    long idx = (long)blockIdx.x * 256 + threadIdx.x;
    if (idx >= (long)ne * 32) return;
    int e = (int)(idx >> 5), f = (int)idx & 31;
    atomicAdd(&agg[(long)col[e] * 32 + f], u[(long)row[e] * 32 + f]);
}

// epilogue: agg = dinv[i]*(agg + u) + bias, fused GraphNorm stats accumulation
__global__ void k_selfbias_stats(float* __restrict__ agg, const float* __restrict__ u,
                                 const float* __restrict__ dinv, const float* __restrict__ bias,
                                 float* __restrict__ sum, float* __restrict__ sumsq, int n) {
    long n4 = (long)n * 8;
    float4 s = {0,0,0,0}, q = {0,0,0,0};
    float4* a4 = (float4*)agg;
    const float4* u4 = (const float4*)u;
    long stride = (long)gridDim.x * 256;
    for (long idx = (long)blockIdx.x * 256 + threadIdx.x; idx < n4; idx += stride) {
        int i = (int)(idx >> 3), fg = ((int)idx & 7) * 4;
        float dc = dinv[i];
        float4 a = a4[idx];
        float4 uv = u4[idx];
        float4 b = *(const float4*)&bias[fg];
        float4 r;
        r.x = dc * (a.x + uv.x) + b.x;
        r.y = dc * (a.y + uv.y) + b.y;
        r.z = dc * (a.z + uv.z) + b.z;
        r.w = dc * (a.w + uv.w) + b.w;
        a4[idx] = r;
        s.x += r.x; s.y += r.y; s.z += r.z; s.w += r.w;
        q.x += r.x * r.x; q.y += r.y * r.y; q.z += r.z * r.z; q.w += r.w * r.w;
    }
    stats_block_reduce(s, q, sum, sumsq);
}

// fused: set mask[pos2[i]]=1 (dedup via atomicExch) and count distinct
__global__ void k_mask_count(const int* __restrict__ pos2, int* __restrict__ mask,
                             int* __restrict__ cnt, int p) {
    int i = blockIdx.x * 256 + threadIdx.x;
    int add = 0;
    if (i < p) {
        int old = atomicExch(&mask[pos2[i]], 1);
        add = (old == 0) ? 1 : 0;
    }
    __shared__ int sd[256];
    sd[threadIdx.x] = add;
    __syncthreads();
    for (int s = 128; s > 0; s >>= 1) {
        if (threadIdx.x < s) sd[threadIdx.x] += sd[threadIdx.x + s];
        __syncthreads();
    }
    if (threadIdx.x == 0 && sd[0]) atomicAdd(cnt, sd[0]);
}

// z has only two distinct rows (mask 0/1); zc{0,1}[o] = z{0,1} @ c2_W[32:48]
__global__ void k_zcalc(const float* __restrict__ emb2, const float* __restrict__ w,
                        const float* __restrict__ b, const float* __restrict__ ms,
                        const int* __restrict__ cnt, const float* __restrict__ c2W,
                        float* __restrict__ zc0, float* __restrict__ zc1) {
    __shared__ float z0[16], z1[16];
    int t = threadIdx.x;  // 32 threads
    const float Mf = (float)M_PAIRS;
    if (t < 16) {
        float e0 = emb2[t], e1 = emb2[16 + t];
        float c1f = (float)(*cnt);
        float mean = (c1f * e1 + (Mf - c1f) * e0) / Mf;
        float c = ms[t] * mean;
        float d0 = e0 - c, d1 = e1 - c;
        float var = (c1f * d1 * d1 + (Mf - c1f) * d0 * d0) / Mf;
        float rs = rsqrtf(var + EPSF);
        z0[t] = w[t] * d0 * rs + b[t];
        z1[t] = w[t] * d1 * rs + b[t];
    }
    __syncthreads();
    float s0 = 0.f, s1 = 0.f;
    #pragma unroll
    for (int f = 0; f < 16; f++) {
        float wv = c2W[(32 + f) * 32 + t];
        s0 += z0[f] * wv;
        s1 += z1[f] * wv;
    }
    zc0[t] = s0;
    zc1[t] = s1;
}

// t2[j][fg..] = (hw[a][fg..] + hw[b][fg..] + zc_{mask[j]}[fg..]) * d2[j]
__global__ void k_t2(const float* __restrict__ hw, const int* __restrict__ pos1,
                     const int* __restrict__ mask, const float* __restrict__ zc0,
                     const float* __restrict__ zc1, const float* __restrict__ d2,
                     float* __restrict__ t2, int m) {
    long idx = (long)blockIdx.x * 256 + threadIdx.x;
    if (idx >= (long)m * 8) return;
    int j = (int)(idx >> 3), fg = ((int)idx & 7) * 4;
    int a = pos1[2 * j], b = pos1[2 * j + 1];
    const float* zc = mask[j] ? zc1 : zc0;
    float dj = d2[j];
    float4 va = *(const float4*)&hw[(long)a * 32 + fg];
    float4 vb = *(const float4*)&hw[(long)b * 32 + fg];
    float4 vz = *(const float4*)&zc[fg];
    float4 r;
    r.x = (va.x + vb.x + vz.x) * dj;
    r.y = (va.y + vb.y + vz.y) * dj;
    r.z = (va.z + vb.z + vz.z) * dj;
    r.w = (va.w + vb.w + vz.w) * dj;
    *(float4*)&t2[idx * 4] = r;
}

// out[k] = relu(A*g2[pos2[k]]+B) . predW + predb
__global__ void k_pred(const float* __restrict__ g2, const int* __restrict__ pos2,
                       const float* __restrict__ A, const float* __restrict__ B,
                       const float* __restrict__ predW, const float* __restrict__ predb,
                       float* __restrict__ out, int p) {
    int k = blockIdx.x * 256 + threadIdx.x;
    if (k >= p) return;
    int j = pos2[k];
    float s = predb[0];
    #pragma unroll
    for (int o = 0; o < 32; o++)
        s += fmaxf(A[o] * g2[(long)j * 32 + o] + B[o], 0.f) * predW[o];
    out[k] = s;
}

extern "C" void kernel_launch(void* const* d_in, const int* in_sizes, int n_in,
                              void* d_out, int out_size, void* d_ws, size_t ws_size,
                              hipStream_t stream) {
    const int*   x      = (const int*)d_in[0];
    const int*   e1row  = (const int*)d_in[1];
    const int*   e1col  = e1row + E1N;
    const int*   e2row  = (const int*)d_in[2];
    const int*   e2col  = e2row + E2N;
    const int*   pos1   = (const int*)d_in[3];
    const int*   pos2   = (const int*)d_in[4];
    const float* emb1   = (const float*)d_in[5];
    const float* gn0_w  = (const float*)d_in[6];
    const float* gn0_b  = (const float*)d_in[7];
    const float* gn0_ms = (const float*)d_in[8];
    const float* c1_W   = (const float*)d_in[9];
    const float* c1_b   = (const float*)d_in[10];
    const float* gn1_w  = (const float*)d_in[11];
    const float* gn1_b  = (const float*)d_in[12];
    const float* gn1_ms = (const float*)d_in[13];
    const float* emb2   = (const float*)d_in[14];
    const float* gn2_w  = (const float*)d_in[15];
    const float* gn2_b  = (const float*)d_in[16];
    const float* gn2_ms = (const float*)d_in[17];
    const float* c2_W   = (const float*)d_in[18];
    const float* c2_b   = (const float*)d_in[19];
    const float* gn3_w  = (const float*)d_in[20];
    const float* gn3_b  = (const float*)d_in[21];
    const float* gn3_ms = (const float*)d_in[22];
    const float* predW  = (const float*)d_in[23];
    const float* predb  = (const float*)d_in[24];
    float* out = (float*)d_out;

    // ---------------- workspace arena (floats) ----------------
    const size_t N32 = (size_t)N_NODES * 32;
    const size_t M32 = (size_t)M_PAIRS * 32;
    float* fw = (float*)d_ws;
    size_t off = 0;
    auto alloc = [&](size_t n) { float* p = fw + off; off += n; return p; };
    float* e    = alloc(N32);               // alias hw later
    float* t    = alloc(N32);               // u1 = (gn0(e)@W + brow) * d1
    float* t2   = alloc(M32);               // u2
    int*   pbuf = (int*)alloc((size_t)NGR * BPG * HWORDS);  // ~33 MB
    float* d1   = alloc(N_NODES);
    float* d2   = alloc(M_PAIRS);
    // ---- contiguous zero region ----
    float* agg  = alloc(N32);
    float* agg2 = alloc(M32);
    int*   mask = (int*)alloc(M_PAIRS);
    float* st   = alloc(S_TOTAL);
    float* hw   = e;  // alias: e dead after k_mm32s

    const size_t zero_bytes = (N32 + M32 + (size_t)M_PAIRS + S_TOTAL) * 4;
    hipMemsetAsync(agg, 0, zero_bytes, stream);

    auto cdiv = [](long a, long b) { return (int)((a + b - 1) / b); };
    const float invN = 1.f / (float)N_NODES;
    const float invM = 1.f / (float)M_PAIRS;

    // ---- degrees via packed LDS partial histograms (no global atomics) ----
    k_deg_hist<<<NGR * BPG, 256, 0, stream>>>(e1col, e2col, pbuf);
    k_deg_reduce<<<cdiv((long)N_NODES + M_PAIRS, 256), 256, 0, stream>>>(pbuf, d1, d2);

    // ---- stage 0: embedding + gn0 stats ----
    k_embed_stats<<<RED_BLOCKS, 256, 0, stream>>>(emb1, x, e, st + S0_SUM, st + S0_SQ, N_NODES);
    k_affine_fold<<<1, 32, 0, stream>>>(st + S0_SUM, st + S0_SQ, gn0_w, gn0_b, gn0_ms, invN,
                                        c1_W, st + S_A0, st + S_B0ROW);

    // ---- conv1: u1 = (gn0(e) @ c1_W) * d1 ; scatter ; epilogue+gn1 stats ----
    k_mm32s<<<cdiv(N_NODES, 8), 256, 0, stream>>>(e, c1_W, st + S_A0, st + S_B0ROW, d1, t, N_NODES);
    k_scatter1<<<cdiv((long)E1N * 32, 256), 256, 0, stream>>>(e1row, e1col, t, agg, E1N);
    k_selfbias_stats<<<RED_BLOCKS, 256, 0, stream>>>(agg, t, d1, c1_b,
                                                     st + S1_SUM, st + S1_SQ, N_NODES);
    k_affine32<<<1, 32, 0, stream>>>(st + S1_SUM, st + S1_SQ, gn1_w, gn1_b, gn1_ms, invN,
                                     st + S_A1, st + S_B1);
    k_mm32_relu_in<<<cdiv(N_NODES, 8), 256, 0, stream>>>(agg, c2_W, st + S_A1, st + S_B1,
                                                         hw, N_NODES);

    // ---- mask / z path ----
    k_mask_count<<<cdiv(P_OUT, 256), 256, 0, stream>>>(pos2, mask, (int*)(st + S_CNT), P_OUT);
    k_zcalc<<<1, 32, 0, stream>>>(emb2, gn2_w, gn2_b, gn2_ms, (const int*)(st + S_CNT),
                                  c2_W, st + S_ZC0, st + S_ZC1);

    // ---- conv2: u2 = (hw[a]+hw[b]+zc) * d2 ; scatter ; epilogue+gn3 stats ----
    k_t2<<<cdiv((long)M_PAIRS * 8, 256), 256, 0, stream>>>(hw, pos1, mask, st + S_ZC0,
                                                           st + S_ZC1, d2, t2, M_PAIRS);
    k_scatter2<<<cdiv((long)E2N * 32, 256), 256, 0, stream>>>(e2row, e2col, t2, agg2, E2N);
    k_selfbias_stats<<<RED_BLOCKS, 256, 0, stream>>>(agg2, t2, d2, c2_b,
                                                     st + S3_SUM, st + S3_SQ, M_PAIRS);
    k_affine32<<<1, 32, 0, stream>>>(st + S3_SUM, st + S3_SQ, gn3_w, gn3_b, gn3_ms, invM,
                                     st + S_A3, st + S_B3);
    k_pred<<<cdiv(P_OUT, 256), 256, 0, stream>>>(agg2, pos2, st + S_A3, st + S_B3,
                                                 predW, predb, out, P_OUT);
}

// Round 15
// 762.306 us; speedup vs baseline: 1.2047x; 1.0010x over previous
//
#include <hip/hip_runtime.h>

#define N_NODES 50000
#define E1N 1600000
#define M_PAIRS 200000
#define E2N 3200000
#define P_OUT 20000
#define EPSF 1e-5f

#define RED_BLOCKS 512
#define RANGE_N 32768          // nodes per histogram group (packed 2/int, 64 KB LDS)
#define HWORDS (RANGE_N / 2)   // 16384 ints
#define NR1 2                  // ceil(N_NODES/RANGE_N)
#define NR2 7                  // ceil(M_PAIRS/RANGE_N)
#define NGR (NR1 + NR2)        // 9 groups
#define BPG 56                 // blocks per group -> 504 blocks ~= 2/CU (LDS limit)

// ---------------- stats offsets within stats buffer (floats) ----------------
#define S0_SUM   0
#define S0_SQ    32
#define S1_SUM   64
#define S1_SQ    96
#define S_CNT    128   // int
#define S3_SUM   160
#define S3_SQ    192
#define S_TOTAL  256

__device__ __forceinline__ void f4add(float4& a, const float4 b) {
    a.x += b.x; a.y += b.y; a.z += b.z; a.w += b.w;
}

// block-level reduce of per-thread float4 partials (feature group = (tid&7)*4)
__device__ __forceinline__ void stats_block_reduce(float4 s, float4 q,
                                                   float* __restrict__ sum,
                                                   float* __restrict__ sumsq) {
    __shared__ float4 ss[256], sq[256];
    int tid = threadIdx.x;
    ss[tid] = s; sq[tid] = q;
    __syncthreads();
    #pragma unroll
    for (int st = 128; st >= 8; st >>= 1) {
        if (tid < st) { f4add(ss[tid], ss[tid + st]); f4add(sq[tid], sq[tid + st]); }
        __syncthreads();
    }
    if (tid < 8) {
        int base = tid * 4;
        float4 fs = ss[tid], fq = sq[tid];
        atomicAdd(&sum[base + 0], fs.x);
        atomicAdd(&sum[base + 1], fs.y);
        atomicAdd(&sum[base + 2], fs.z);
        atomicAdd(&sum[base + 3], fs.w);
        atomicAdd(&sumsq[base + 0], fq.x);
        atomicAdd(&sumsq[base + 1], fq.y);
        atomicAdd(&sumsq[base + 2], fq.z);
        atomicAdd(&sumsq[base + 3], fq.w);
    }
}

// per-feature GraphNorm affine from global sums (device helper, 32 callers/block)
__device__ __forceinline__ void gn_affine(int f, const float* __restrict__ sum,
                                          const float* __restrict__ sumsq,
                                          const float* __restrict__ w,
                                          const float* __restrict__ b,
                                          const float* __restrict__ ms, float invN,
                                          float& A, float& B) {
    float mean = sum[f] * invN;
    float c = ms[f] * mean;
    float var = sumsq[f] * invN - 2.f * c * mean + c * c;
    float rs = rsqrtf(var + EPSF);
    A = w[f] * rs;
    B = b[f] - w[f] * rs * c;
}

// gather embedding rows (float4 granularity), store e, accumulate gn0 stats
__global__ void k_embed_stats(const float* __restrict__ emb, const int* __restrict__ x,
                              float* __restrict__ e, float* __restrict__ sum,
                              float* __restrict__ sumsq, int n) {
    long n4 = (long)n * 8;
    float4 s = {0,0,0,0}, q = {0,0,0,0};
    float4* e4 = (float4*)e;
    long stride = (long)gridDim.x * 256;
    for (long i = (long)blockIdx.x * 256 + threadIdx.x; i < n4; i += stride) {
        int node = (int)(i >> 3), fg = ((int)i & 7) * 4;
        int xr = x[node];
        float4 v = *(const float4*)&emb[(long)xr * 32 + fg];
        e4[i] = v;
        s.x += v.x; s.y += v.y; s.z += v.z; s.w += v.w;
        q.x += v.x * v.x; q.y += v.y * v.y; q.z += v.z * v.z; q.w += v.w * v.w;
    }
    stats_block_reduce(s, q, sum, sumsq);
}

// u[i][o] = (sum_f (A0[f]*e[i][f]) * W[f][o] + brow[o]) * dscale[i]
// gn0 affine + bias-fold computed per block (fused, removes 1-wave kernels)
__global__ void k_mm32s(const float* __restrict__ e, const float* __restrict__ W,
                        const float* __restrict__ sum, const float* __restrict__ sumsq,
                        const float* __restrict__ gw, const float* __restrict__ gb,
                        const float* __restrict__ gms, float invN,
                        const float* __restrict__ dscale, float* __restrict__ t, int n) {
    __shared__ float Wp[32][32];
    __shared__ float rows[8][32];
    __shared__ float As[32], Bl[32], brow[32];
    int lt = threadIdx.x;
    if (lt < 32) {
        float A, B;
        gn_affine(lt, sum, sumsq, gw, gb, gms, invN, A, B);
        As[lt] = A; Bl[lt] = B;
    }
    __syncthreads();
    for (int k = lt; k < 1024; k += 256) {
        int f = k >> 5;
        Wp[f][k & 31] = As[f] * W[k];
    }
    if (lt < 32) {
        float s = 0.f;
        #pragma unroll
        for (int f = 0; f < 32; f++) s += Bl[f] * W[f * 32 + lt];
        brow[lt] = s;
    }
    int nl = lt >> 5, o = lt & 31;
    int node = blockIdx.x * 8 + nl;
    if (node < n) rows[nl][o] = e[(long)node * 32 + o];
    __syncthreads();
    if (node < n) {
        float acc = brow[o];
        #pragma unroll
        for (int f = 0; f < 32; f++) acc += rows[nl][f] * Wp[f][o];
        t[(long)node * 32 + o] = acc * dscale[node];
    }
}

// hw[i][o] = sum_f relu(A1[f]*g[i][f]+B1[f]) * W[f][o]  (gn1 affine computed per block)
__global__ void k_mm32_relu_in(const float* __restrict__ g, const float* __restrict__ W,
                               const float* __restrict__ sum, const float* __restrict__ sumsq,
                               const float* __restrict__ gw, const float* __restrict__ gb,
                               const float* __restrict__ gms, float invN,
                               float* __restrict__ hw, int n) {
    __shared__ float Wp[32][32];
    __shared__ float rows[8][32];
    __shared__ float As[32], Bs[32];
    int lt = threadIdx.x;
    if (lt < 32) {
        float A, B;
        gn_affine(lt, sum, sumsq, gw, gb, gms, invN, A, B);
        As[lt] = A; Bs[lt] = B;
    }
    __syncthreads();
    for (int k = lt; k < 1024; k += 256) {
        Wp[k >> 5][k & 31] = W[k];
    }
    int nl = lt >> 5, o = lt & 31;
    int node = blockIdx.x * 8 + nl;
    if (node < n) rows[nl][o] = fmaxf(As[o] * g[(long)node * 32 + o] + Bs[o], 0.f);
    __syncthreads();
    if (node < n) {
        float acc = 0.f;
        #pragma unroll
        for (int f = 0; f < 32; f++) acc += rows[nl][f] * Wp[f][o];
        hw[(long)node * 32 + o] = acc;
    }
}

// ---------------- degree via PACKED 16-bit LDS histograms ----------------
__global__ __launch_bounds__(256) void k_deg_hist(const int* __restrict__ e1col,
                                                  const int* __restrict__ e2col,
                                                  int* __restrict__ pbuf) {
    __shared__ int h[HWORDS];   // 64 KB
    int tid = threadIdx.x;
    for (int i = tid; i < HWORDS; i += 256) h[i] = 0;
    __syncthreads();
    int gid = blockIdx.x / BPG;
    int blk = blockIdx.x % BPG;
    const int* col; long ne; int base;
    if (gid < NR1) { col = e1col; ne = E1N; base = gid * RANGE_N; }
    else           { col = e2col; ne = E2N; base = (gid - NR1) * RANGE_N; }
    for (long i = (long)blk * 256 + tid; i < ne; i += (long)BPG * 256) {
        unsigned c = (unsigned)(col[i] - base);
        if (c < RANGE_N) atomicAdd(&h[c >> 1], 1 << ((c & 1) * 16));
    }
    __syncthreads();
    int* dst = pbuf + ((size_t)gid * BPG + blk) * HWORDS;
    for (int i = tid; i < HWORDS; i += 256) dst[i] = h[i];
}

// reduce BPG packed partials per node -> dinv = rsqrt(deg+1); both graphs
__global__ void k_deg_reduce(const int* __restrict__ pbuf,
                             float* __restrict__ d1, float* __restrict__ d2) {
    int idx = blockIdx.x * 256 + threadIdx.x;
    if (idx < N_NODES) {
        int g = idx / RANGE_N, off = idx % RANGE_N;
        const int* p = pbuf + ((size_t)g * BPG) * HWORDS + (off >> 1);
        int sh = (off & 1) * 16;
        int s = 0;
        #pragma unroll
        for (int b = 0; b < BPG; b++) s += (p[(size_t)b * HWORDS] >> sh) & 0xFFFF;
        d1[idx] = rsqrtf((float)s + 1.f);
    } else if (idx - N_NODES < M_PAIRS) {
        int j = idx - N_NODES;
        int g = j / RANGE_N, off = j % RANGE_N;
        const int* p = pbuf + ((size_t)(NR1 + g) * BPG) * HWORDS + (off >> 1);
        int sh = (off & 1) * 16;
        int s = 0;
        #pragma unroll
        for (int b = 0; b < BPG; b++) s += (p[(size_t)b * HWORDS] >> sh) & 0xFFFF;
        d2[j] = rsqrtf((float)s + 1.f);
    }
}

// coalesced atomic scatter: agg[col][f] += u[row][f]   (conv1 instance)
__global__ void k_scatter1(const int* __restrict__ row, const int* __restrict__ col,
                           const float* __restrict__ u, float* __restrict__ agg, int ne) {
    long idx = (long)blockIdx.x * 256 + threadIdx.x;
    if (idx >= (long)ne * 32) return;
    int e = (int)(idx >> 5), f = (int)idx & 31;
    atomicAdd(&agg[(long)col[e] * 32 + f], u[(long)row[e] * 32 + f]);
}

// identical body, distinct symbol for profiling (conv2 instance)
__global__ void k_scatter2(const int* __restrict__ row, const int* __restrict__ col,
                           const float* __restrict__ u, float* __restrict__ agg, int ne) {
    long idx = (long)blockIdx.x * 256 + threadIdx.x;
    if (idx >= (long)ne * 32) return;
    int e = (int)(idx >> 5), f = (int)idx & 31;
    atomicAdd(&agg[(long)col[e] * 32 + f], u[(long)row[e] * 32 + f]);
}

// epilogue: agg = dinv[i]*(agg + u) + bias, fused GraphNorm stats accumulation
__global__ void k_selfbias_stats(float* __restrict__ agg, const float* __restrict__ u,
                                 const float* __restrict__ dinv, const float* __restrict__ bias,
                                 float* __restrict__ sum, float* __restrict__ sumsq, int n) {
    long n4 = (long)n * 8;
    float4 s = {0,0,0,0}, q = {0,0,0,0};
    float4* a4 = (float4*)agg;
    const float4* u4 = (const float4*)u;
    long stride = (long)gridDim.x * 256;
    for (long idx = (long)blockIdx.x * 256 + threadIdx.x; idx < n4; idx += stride) {
        int i = (int)(idx >> 3), fg = ((int)idx & 7) * 4;
        float dc = dinv[i];
        float4 a = a4[idx];
        float4 uv = u4[idx];
        float4 b = *(const float4*)&bias[fg];
        float4 r;
        r.x = dc * (a.x + uv.x) + b.x;
        r.y = dc * (a.y + uv.y) + b.y;
        r.z = dc * (a.z + uv.z) + b.z;
        r.w = dc * (a.w + uv.w) + b.w;
        a4[idx] = r;
        s.x += r.x; s.y += r.y; s.z += r.z; s.w += r.w;
        q.x += r.x * r.x; q.y += r.y * r.y; q.z += r.z * r.z; q.w += r.w * r.w;
    }
    stats_block_reduce(s, q, sum, sumsq);
}

// fused: set mask[pos2[i]]=1 (dedup via atomicExch) and count distinct
__global__ void k_mask_count(const int* __restrict__ pos2, int* __restrict__ mask,
                             int* __restrict__ cnt, int p) {
    int i = blockIdx.x * 256 + threadIdx.x;
    int add = 0;
    if (i < p) {
        int old = atomicExch(&mask[pos2[i]], 1);
        add = (old == 0) ? 1 : 0;
    }
    __shared__ int sd[256];
    sd[threadIdx.x] = add;
    __syncthreads();
    for (int s = 128; s > 0; s >>= 1) {
        if (threadIdx.x < s) sd[threadIdx.x] += sd[threadIdx.x + s];
        __syncthreads();
    }
    if (threadIdx.x == 0 && sd[0]) atomicAdd(cnt, sd[0]);
}

// t2[j][fg..] = (hw[a][fg..] + hw[b][fg..] + zc_{mask[j]}[fg..]) * d2[j]
// zc0/zc1 (the two distinct z-rows pushed through c2_W[32:48]) computed per block
__global__ void k_t2(const float* __restrict__ hw, const int* __restrict__ pos1,
                     const int* __restrict__ mask,
                     const float* __restrict__ emb2, const float* __restrict__ gw,
                     const float* __restrict__ gb, const float* __restrict__ gms,
                     const int* __restrict__ cnt, const float* __restrict__ c2W,
                     const float* __restrict__ d2, float* __restrict__ t2, int m) {
    __shared__ float z0[16], z1[16], zc0[32], zc1[32];
    int lt = threadIdx.x;
    if (lt < 16) {
        const float Mf = (float)M_PAIRS;
        float e0 = emb2[lt], e1 = emb2[16 + lt];
        float c1f = (float)(*cnt);
        float mean = (c1f * e1 + (Mf - c1f) * e0) / Mf;
        float c = gms[lt] * mean;
        float dd0 = e0 - c, dd1 = e1 - c;
        float var = (c1f * dd1 * dd1 + (Mf - c1f) * dd0 * dd0) / Mf;
        float rs = rsqrtf(var + EPSF);
        z0[lt] = gw[lt] * dd0 * rs + gb[lt];
        z1[lt] = gw[lt] * dd1 * rs + gb[lt];
    }
    __syncthreads();
    if (lt < 32) {
        float s0 = 0.f, s1 = 0.f;
        #pragma unroll
        for (int f = 0; f < 16; f++) {
            float wv = c2W[(32 + f) * 32 + lt];
            s0 += z0[f] * wv;
            s1 += z1[f] * wv;
        }
        zc0[lt] = s0;
        zc1[lt] = s1;
    }
    __syncthreads();
    long idx = (long)blockIdx.x * 256 + lt;
    if (idx >= (long)m * 8) return;
    int j = (int)(idx >> 3), fg = ((int)idx & 7) * 4;
    int a = pos1[2 * j], b = pos1[2 * j + 1];
    const float* zc = mask[j] ? zc1 : zc0;
    float dj = d2[j];
    float4 va = *(const float4*)&hw[(long)a * 32 + fg];
    float4 vb = *(const float4*)&hw[(long)b * 32 + fg];
    float4 vz = *(const float4*)&zc[fg];
    float4 r;
    r.x = (va.x + vb.x + vz.x) * dj;
    r.y = (va.y + vb.y + vz.y) * dj;
    r.z = (va.z + vb.z + vz.z) * dj;
    r.w = (va.w + vb.w + vz.w) * dj;
    *(float4*)&t2[idx * 4] = r;
}

// out[k] = relu(A3*g2[pos2[k]]+B3) . predW + predb   (gn3 affine computed per block)
__global__ void k_pred(const float* __restrict__ g2, const int* __restrict__ pos2,
                       const float* __restrict__ sum, const float* __restrict__ sumsq,
                       const float* __restrict__ gw, const float* __restrict__ gb,
                       const float* __restrict__ gms, float invM,
                       const float* __restrict__ predW, const float* __restrict__ predb,
                       float* __restrict__ out, int p) {
    __shared__ float As[32], Bs[32];
    if (threadIdx.x < 32) {
        float A, B;
        gn_affine(threadIdx.x, sum, sumsq, gw, gb, gms, invM, A, B);
        As[threadIdx.x] = A; Bs[threadIdx.x] = B;
    }
    __syncthreads();
    int k = blockIdx.x * 256 + threadIdx.x;
    if (k >= p) return;
    int j = pos2[k];
    float s = predb[0];
    #pragma unroll
    for (int o = 0; o < 32; o++)
        s += fmaxf(As[o] * g2[(long)j * 32 + o] + Bs[o], 0.f) * predW[o];
    out[k] = s;
}

extern "C" void kernel_launch(void* const* d_in, const int* in_sizes, int n_in,
                              void* d_out, int out_size, void* d_ws, size_t ws_size,
                              hipStream_t stream) {
    const int*   x      = (const int*)d_in[0];
    const int*   e1row  = (const int*)d_in[1];
    const int*   e1col  = e1row + E1N;
    const int*   e2row  = (const int*)d_in[2];
    const int*   e2col  = e2row + E2N;
    const int*   pos1   = (const int*)d_in[3];
    const int*   pos2   = (const int*)d_in[4];
    const float* emb1   = (const float*)d_in[5];
    const float* gn0_w  = (const float*)d_in[6];
    const float* gn0_b  = (const float*)d_in[7];
    const float* gn0_ms = (const float*)d_in[8];
    const float* c1_W   = (const float*)d_in[9];
    const float* c1_b   = (const float*)d_in[10];
    const float* gn1_w  = (const float*)d_in[11];
    const float* gn1_b  = (const float*)d_in[12];
    const float* gn1_ms = (const float*)d_in[13];
    const float* emb2   = (const float*)d_in[14];
    const float* gn2_w  = (const float*)d_in[15];
    const float* gn2_b  = (const float*)d_in[16];
    const float* gn2_ms = (const float*)d_in[17];
    const float* c2_W   = (const float*)d_in[18];
    const float* c2_b   = (const float*)d_in[19];
    const float* gn3_w  = (const float*)d_in[20];
    const float* gn3_b  = (const float*)d_in[21];
    const float* gn3_ms = (const float*)d_in[22];
    const float* predW  = (const float*)d_in[23];
    const float* predb  = (const float*)d_in[24];
    float* out = (float*)d_out;

    // ---------------- workspace arena (floats) ----------------
    const size_t N32 = (size_t)N_NODES * 32;
    const size_t M32 = (size_t)M_PAIRS * 32;
    float* fw = (float*)d_ws;
    size_t off = 0;
    auto alloc = [&](size_t n) { float* p = fw + off; off += n; return p; };
    float* e    = alloc(N32);               // alias hw later
    float* t    = alloc(N32);               // u1 = (gn0(e)@W + brow) * d1
    float* t2   = alloc(M32);               // u2
    int*   pbuf = (int*)alloc((size_t)NGR * BPG * HWORDS);  // ~33 MB
    float* d1   = alloc(N_NODES);
    float* d2   = alloc(M_PAIRS);
    // ---- contiguous zero region ----
    float* agg  = alloc(N32);
    float* agg2 = alloc(M32);
    int*   mask = (int*)alloc(M_PAIRS);
    float* st   = alloc(S_TOTAL);
    float* hw   = e;  // alias: e dead after k_mm32s

    const size_t zero_bytes = (N32 + M32 + (size_t)M_PAIRS + S_TOTAL) * 4;
    hipMemsetAsync(agg, 0, zero_bytes, stream);

    auto cdiv = [](long a, long b) { return (int)((a + b - 1) / b); };
    const float invN = 1.f / (float)N_NODES;
    const float invM = 1.f / (float)M_PAIRS;

    // ---- degrees via packed LDS partial histograms (no global atomics) ----
    k_deg_hist<<<NGR * BPG, 256, 0, stream>>>(e1col, e2col, pbuf);
    k_deg_reduce<<<cdiv((long)N_NODES + M_PAIRS, 256), 256, 0, stream>>>(pbuf, d1, d2);

    // ---- stage 0: embedding + gn0 stats ----
    k_embed_stats<<<RED_BLOCKS, 256, 0, stream>>>(emb1, x, e, st + S0_SUM, st + S0_SQ, N_NODES);

    // ---- conv1: u1 = (gn0(e) @ c1_W) * d1 ; scatter ; epilogue+gn1 stats ----
    k_mm32s<<<cdiv(N_NODES, 8), 256, 0, stream>>>(e, c1_W, st + S0_SUM, st + S0_SQ,
                                                  gn0_w, gn0_b, gn0_ms, invN, d1, t, N_NODES);
    k_scatter1<<<cdiv((long)E1N * 32, 256), 256, 0, stream>>>(e1row, e1col, t, agg, E1N);
    k_selfbias_stats<<<RED_BLOCKS, 256, 0, stream>>>(agg, t, d1, c1_b,
                                                     st + S1_SUM, st + S1_SQ, N_NODES);
    k_mm32_relu_in<<<cdiv(N_NODES, 8), 256, 0, stream>>>(agg, c2_W, st + S1_SUM, st + S1_SQ,
                                                         gn1_w, gn1_b, gn1_ms, invN,
                                                         hw, N_NODES);

    // ---- mask / z path ----
    k_mask_count<<<cdiv(P_OUT, 256), 256, 0, stream>>>(pos2, mask, (int*)(st + S_CNT), P_OUT);

    // ---- conv2: u2 = (hw[a]+hw[b]+zc) * d2 ; scatter ; epilogue+gn3 stats ----
    k_t2<<<cdiv((long)M_PAIRS * 8, 256), 256, 0, stream>>>(hw, pos1, mask,
                                                           emb2, gn2_w, gn2_b, gn2_ms,
                                                           (const int*)(st + S_CNT), c2_W,
                                                           d2, t2, M_PAIRS);
    k_scatter2<<<cdiv((long)E2N * 32, 256), 256, 0, stream>>>(e2row, e2col, t2, agg2, E2N);
    k_selfbias_stats<<<RED_BLOCKS, 256, 0, stream>>>(agg2, t2, d2, c2_b,
                                                     st + S3_SUM, st + S3_SQ, M_PAIRS);
    k_pred<<<cdiv(P_OUT, 256), 256, 0, stream>>>(agg2, pos2, st + S3_SUM, st + S3_SQ,
                                                 gn3_w, gn3_b, gn3_ms, invM,
                                                 predW, predb, out, P_OUT);
}